// Round 1
// baseline (867.601 us; speedup 1.0000x reference)
//
#include <hip/hip_runtime.h>
#include <math.h>

#define T_STEPS 19
#define V 50257
#define EMB 300
#define HDIM 512
#define NP 256
#define ML 50
#define CIN 812
#define NEGV -1e9f

// ---- workspace layout (floats) ----
#define OFF_X      0                      // 19*300 = 5700
#define OFF_POP    5700                   // 19*256 = 4864
#define OFF_PL     (OFF_POP + 4864)       // 19*256 = 4864
#define OFF_PC     (OFF_PL + 4864)        // 19*512 = 9728
#define OFF_HS     (OFF_PC + 9728)        // 20*512 = 10240 (Hs[0]=input hidden)
#define OFF_H1OP   (OFF_HS + 10240)       // 256
#define OFF_H1L    (OFF_H1OP + 256)       // 256
#define OFF_GH     (OFF_H1L + 256)        // 1536
#define OFF_CTXOP  (OFF_GH + 1536)        // 256
#define OFF_CTXL   (OFF_CTXOP + 256)      // 256
#define OFF_C1     (OFF_CTXL + 256)       // 512
#define OFF_G      (OFF_C1 + 512)         // 512

// ---- output layout (floats) ----
#define OUT_LOGITS 0
#define OUT_ATTW   ((long)T_STEPS * V)                 // 19*50
#define OUT_ATTOB  (OUT_ATTW + (long)T_STEPS * ML)     // 19*256

__device__ __forceinline__ float wred(float v) {
  v += __shfl_xor(v, 32, 64);
  v += __shfl_xor(v, 16, 64);
  v += __shfl_xor(v, 8, 64);
  v += __shfl_xor(v, 4, 64);
  v += __shfl_xor(v, 2, 64);
  v += __shfl_xor(v, 1, 64);
  return v;
}

__device__ __forceinline__ float dot4(float4 a, float4 b) {
  return a.x * b.x + a.y * b.y + a.z * b.z + a.w * b.w;
}

// Precompute X = relu(emb[token]) for all steps, and copy Hs[0]=hidden.
__global__ void k_pre1(const int* __restrict__ tok0, const int* __restrict__ ans,
                       const float* __restrict__ emb, const float* __restrict__ hidden,
                       float* __restrict__ ws) {
  int tid = blockIdx.x * 256 + threadIdx.x;
  if (tid < T_STEPS * EMB) {
    int s = tid / EMB, j = tid - s * EMB;
    int t = (s == 0) ? tok0[0] : ans[s];
    float v = emb[(long)t * EMB + j];
    ws[OFF_X + tid] = v > 0.f ? v : 0.f;
  } else {
    int k = tid - T_STEPS * EMB;
    if (k < HDIM) ws[OFF_HS + k] = hidden[k];
  }
}

// P_op[s][r], P_l[s][r], P_c[s][r]: x-column partial dots + layer-1 biases.
// wave-per-row; 19*1024 rows total.
__global__ void k_pre2(const float* __restrict__ w1op, const float* __restrict__ b1op,
                       const float* __restrict__ w1l,  const float* __restrict__ b1l,
                       const float* __restrict__ wc1,  const float* __restrict__ bc1,
                       float* __restrict__ ws) {
  int gw = (blockIdx.x * 256 + threadIdx.x) >> 6;
  int lane = threadIdx.x & 63;
  int s = gw >> 10;
  int rr = gw & 1023;
  if (s >= T_STEPS) return;
  const float* wrow; const float* bias; float* dst; int r;
  if (rr < 256)      { r = rr;       wrow = w1op + (long)r * CIN; bias = b1op; dst = ws + OFF_POP + s * 256 + r; }
  else if (rr < 512) { r = rr - 256; wrow = w1l  + (long)r * CIN; bias = b1l;  dst = ws + OFF_PL  + s * 256 + r; }
  else               { r = rr - 512; wrow = wc1  + (long)r * CIN; bias = bc1;  dst = ws + OFF_PC  + s * 512 + r; }
  const float* x = ws + OFF_X + s * EMB;
  float acc = 0.f;
#pragma unroll
  for (int it = 0; it < 5; ++it) {
    int j = it * 64 + lane;
    if (j < EMB) acc += wrow[j] * x[j];
  }
  acc = wred(acc);
  if (lane == 0) *dst = acc + bias[r];
}

// Per step: h1op (256), h1l (256), gh (1536) — all depend only on h.
__global__ void k_step1(const float* __restrict__ w1op, const float* __restrict__ w1l,
                        const float* __restrict__ whh,  const float* __restrict__ bhh,
                        float* __restrict__ ws, int s) {
  int gw = (blockIdx.x * 256 + threadIdx.x) >> 6;
  int lane = threadIdx.x & 63;
  const float* h = ws + OFF_HS + s * HDIM;
  float4 ha = *(const float4*)(h + 4 * lane);
  float4 hb = *(const float4*)(h + 256 + 4 * lane);
  const float* wrow; float extra; float* dst; int isrelu;
  if (gw < 256) {
    int r = gw;        wrow = w1op + (long)r * CIN + 300; extra = ws[OFF_POP + s * 256 + r]; dst = ws + OFF_H1OP + r; isrelu = 1;
  } else if (gw < 512) {
    int r = gw - 256;  wrow = w1l  + (long)r * CIN + 300; extra = ws[OFF_PL  + s * 256 + r]; dst = ws + OFF_H1L  + r; isrelu = 1;
  } else {
    int r = gw - 512;  wrow = whh  + (long)r * HDIM;      extra = bhh[r];                    dst = ws + OFF_GH   + r; isrelu = 0;
  }
  float4 wa = *(const float4*)(wrow + 4 * lane);
  float4 wb = *(const float4*)(wrow + 256 + 4 * lane);
  float acc = dot4(wa, ha) + dot4(wb, hb);
  acc = wred(acc);
  if (lane == 0) {
    float v = acc + extra;
    if (isrelu && v < 0.f) v = 0.f;
    *dst = v;
  }
}

// Per step: attention logits, masked softmax, context vectors. 2 blocks.
__global__ void k_step2(const float* __restrict__ w2op, const float* __restrict__ b2op,
                        const float* __restrict__ w2l,  const float* __restrict__ b2l,
                        const int* __restrict__ obj_mask, const int* __restrict__ lang_mask,
                        const float* __restrict__ prop, const float* __restrict__ enc,
                        float* __restrict__ ws, float* __restrict__ out, int s) {
  __shared__ float lds_v[256];
  __shared__ float lds_r[256];
  int tid = threadIdx.x;
  int wv = tid >> 6, lane = tid & 63;
  if (blockIdx.x == 0) {
    // ---- object attention ----
    const float* h1 = ws + OFF_H1OP;
    float4 ha = *(const float4*)(h1 + 4 * lane);
    for (int i = 0; i < 64; ++i) {
      int r = wv * 64 + i;
      float4 w4 = *(const float4*)(w2op + (long)r * 256 + 4 * lane);
      float acc = wred(dot4(w4, ha));
      if (lane == 0) lds_v[r] = acc + b2op[r];
    }
    __syncthreads();
    float v = (obj_mask[tid] != 0) ? NEGV : lds_v[tid];
    lds_r[tid] = v; __syncthreads();
    for (int st = 128; st > 0; st >>= 1) { if (tid < st) lds_r[tid] = fmaxf(lds_r[tid], lds_r[tid + st]); __syncthreads(); }
    float m = lds_r[0]; __syncthreads();
    float e = expf(v - m);
    lds_r[tid] = e; __syncthreads();
    for (int st = 128; st > 0; st >>= 1) { if (tid < st) lds_r[tid] += lds_r[tid + st]; __syncthreads(); }
    float a = e / lds_r[0];
    out[OUT_ATTOB + (long)s * NP + tid] = a;
    __syncthreads();           // lds_v free to reuse
    lds_v[tid] = a; __syncthreads();
    float acc = 0.f;
#pragma unroll 8
    for (int k = 0; k < 256; ++k) acc += lds_v[k] * prop[k * 256 + tid];
    ws[OFF_CTXOP + tid] = acc;
  } else {
    // ---- language attention ----
    const float* h1 = ws + OFF_H1L;
    float4 ha = *(const float4*)(h1 + 4 * lane);
    for (int i = 0; i < 13; ++i) {
      int r = wv + 4 * i;
      if (r < ML) {
        float4 w4 = *(const float4*)(w2l + (long)r * 256 + 4 * lane);
        float acc = wred(dot4(w4, ha));
        if (lane == 0) lds_v[r] = acc + b2l[r];
      }
    }
    __syncthreads();
    float v = (tid < ML) ? ((lang_mask[tid] != 0) ? NEGV : lds_v[tid]) : -3e38f;
    lds_r[tid] = v; __syncthreads();
    for (int st = 128; st > 0; st >>= 1) { if (tid < st) lds_r[tid] = fmaxf(lds_r[tid], lds_r[tid + st]); __syncthreads(); }
    float m = lds_r[0]; __syncthreads();
    float e = (tid < ML) ? expf(v - m) : 0.f;
    lds_r[tid] = e; __syncthreads();
    for (int st = 128; st > 0; st >>= 1) { if (tid < st) lds_r[tid] += lds_r[tid + st]; __syncthreads(); }
    float den = lds_r[0];
    __syncthreads();
    if (tid < ML) {
      float a = e / den;
      out[OUT_ATTW + (long)s * ML + tid] = a;
      lds_v[tid] = a;
    }
    __syncthreads();
    float acc = 0.f;
#pragma unroll 5
    for (int k = 0; k < ML; ++k) acc += lds_v[k] * enc[k * 256 + tid];
    ws[OFF_CTXL + tid] = acc;
  }
}

// Per step: c1 = relu(P_c + W[ctx cols]@ctx + W[ctxop cols]@ctx_op)
__global__ void k_step3(const float* __restrict__ wc1, float* __restrict__ ws, int s) {
  int gw = (blockIdx.x * 256 + threadIdx.x) >> 6;
  int lane = threadIdx.x & 63;
  int r = gw;  // 0..511
  const float* wr = wc1 + (long)r * CIN;
  float4 wa = *(const float4*)(wr + 300 + 4 * lane);
  float4 wb = *(const float4*)(wr + 556 + 4 * lane);
  float4 ca = *(const float4*)(ws + OFF_CTXL + 4 * lane);
  float4 cb = *(const float4*)(ws + OFF_CTXOP + 4 * lane);
  float acc = wred(dot4(wa, ca) + dot4(wb, cb));
  if (lane == 0) {
    float v = acc + ws[OFF_PC + s * HDIM + r];
    ws[OFF_C1 + r] = v > 0.f ? v : 0.f;
  }
}

// Per step: g = relu(cmb_w2 @ c1 + b2)
__global__ void k_step4(const float* __restrict__ wc2, const float* __restrict__ bc2,
                        float* __restrict__ ws, int s) {
  (void)s;
  int gw = (blockIdx.x * 256 + threadIdx.x) >> 6;
  int lane = threadIdx.x & 63;
  int r = gw;  // 0..511
  const float* wr = wc2 + (long)r * HDIM;
  float4 wa = *(const float4*)(wr + 4 * lane);
  float4 wb = *(const float4*)(wr + 256 + 4 * lane);
  float4 ca = *(const float4*)(ws + OFF_C1 + 4 * lane);
  float4 cb = *(const float4*)(ws + OFF_C1 + 256 + 4 * lane);
  float acc = wred(dot4(wa, ca) + dot4(wb, cb));
  if (lane == 0) {
    float v = acc + bc2[r];
    ws[OFF_G + r] = v > 0.f ? v : 0.f;
  }
}

// Per step: GRU — gi rows j, j+512, j+1024, fuse gates -> h_new
__global__ void k_step5(const float* __restrict__ wih, const float* __restrict__ bih,
                        float* __restrict__ ws, int s) {
  int gw = (blockIdx.x * 256 + threadIdx.x) >> 6;
  int lane = threadIdx.x & 63;
  int j = gw;  // 0..511
  const float* gvec = ws + OFF_G;
  float4 ga = *(const float4*)(gvec + 4 * lane);
  float4 gb = *(const float4*)(gvec + 256 + 4 * lane);
  const float* w0 = wih + (long)j * HDIM;
  const float* w1 = wih + (long)(j + 512) * HDIM;
  const float* w2 = wih + (long)(j + 1024) * HDIM;
  float a0 = dot4(*(const float4*)(w0 + 4 * lane), ga) + dot4(*(const float4*)(w0 + 256 + 4 * lane), gb);
  float a1 = dot4(*(const float4*)(w1 + 4 * lane), ga) + dot4(*(const float4*)(w1 + 256 + 4 * lane), gb);
  float a2 = dot4(*(const float4*)(w2 + 4 * lane), ga) + dot4(*(const float4*)(w2 + 256 + 4 * lane), gb);
  a0 = wred(a0); a1 = wred(a1); a2 = wred(a2);
  if (lane == 0) {
    float ir = a0 + bih[j];
    float iz = a1 + bih[512 + j];
    float in_ = a2 + bih[1024 + j];
    float hr = ws[OFF_GH + j];
    float hz = ws[OFF_GH + 512 + j];
    float hn = ws[OFF_GH + 1024 + j];
    float rg = 1.f / (1.f + expf(-(ir + hr)));
    float zg = 1.f / (1.f + expf(-(iz + hz)));
    float ng = tanhf(in_ + rg * hn);
    float hprev = ws[OFF_HS + s * HDIM + j];
    ws[OFF_HS + (s + 1) * HDIM + j] = (1.f - zg) * ng + zg * hprev;
  }
}

// Final: logits[s][r] = Hs[s+1] . out_w[r] + out_b[r] for all 19 s, 50257 r.
// Wave-per-row; H (19x512) held in VGPRs (152 regs), butterfly reduce.
__global__ void __launch_bounds__(256) k_final(const float* __restrict__ ow,
                                               const float* __restrict__ ob,
                                               const float* __restrict__ ws,
                                               float* __restrict__ out) {
  int gw = (blockIdx.x * 256 + threadIdx.x) >> 6;
  int lane = threadIdx.x & 63;
  int nw = gridDim.x * 4;
  const float* hs = ws + OFF_HS + HDIM;  // Hs[1..19]
  float4 HA[T_STEPS], HB[T_STEPS];
#pragma unroll
  for (int s = 0; s < T_STEPS; ++s) {
    HA[s] = *(const float4*)(hs + s * HDIM + 4 * lane);
    HB[s] = *(const float4*)(hs + s * HDIM + 256 + 4 * lane);
  }
  for (int r = gw; r < V; r += nw) {
    const float* wr = ow + (long)r * HDIM;
    float4 wa = *(const float4*)(wr + 4 * lane);
    float4 wb = *(const float4*)(wr + 256 + 4 * lane);
    float acc[T_STEPS];
#pragma unroll
    for (int s = 0; s < T_STEPS; ++s) acc[s] = dot4(wa, HA[s]) + dot4(wb, HB[s]);
#pragma unroll
    for (int s = 0; s < T_STEPS; ++s) acc[s] = wred(acc[s]);
    if (lane == 0) {
      float bias = ob[r];
#pragma unroll
      for (int s = 0; s < T_STEPS; ++s) out[OUT_LOGITS + (long)s * V + r] = acc[s] + bias;
    }
  }
}

extern "C" void kernel_launch(void* const* d_in, const int* in_sizes, int n_in,
                              void* d_out, int out_size, void* d_ws, size_t ws_size,
                              hipStream_t stream) {
  const int*   input_tok   = (const int*)d_in[0];
  const float* hidden      = (const float*)d_in[1];
  const float* enc         = (const float*)d_in[2];
  const float* prop        = (const float*)d_in[3];
  const int*   obj_mask    = (const int*)d_in[4];
  const int*   lang_mask   = (const int*)d_in[5];
  const int*   ans         = (const int*)d_in[6];
  const float* emb         = (const float*)d_in[7];
  const float* attn_w1     = (const float*)d_in[8];
  const float* attn_b1     = (const float*)d_in[9];
  const float* attn_w2     = (const float*)d_in[10];
  const float* attn_b2     = (const float*)d_in[11];
  const float* attn_op_w1  = (const float*)d_in[12];
  const float* attn_op_b1  = (const float*)d_in[13];
  const float* attn_op_w2  = (const float*)d_in[14];
  const float* attn_op_b2  = (const float*)d_in[15];
  const float* cmb_w1      = (const float*)d_in[16];
  const float* cmb_b1      = (const float*)d_in[17];
  const float* cmb_w2      = (const float*)d_in[18];
  const float* cmb_b2      = (const float*)d_in[19];
  const float* gw_ih       = (const float*)d_in[20];
  const float* gw_hh       = (const float*)d_in[21];
  const float* gb_ih       = (const float*)d_in[22];
  const float* gb_hh       = (const float*)d_in[23];
  const float* out_w       = (const float*)d_in[24];
  const float* out_b       = (const float*)d_in[25];
  float* out = (float*)d_out;
  float* ws  = (float*)d_ws;

  k_pre1<<<25, 256, 0, stream>>>(input_tok, ans, emb, hidden, ws);
  k_pre2<<<4864, 256, 0, stream>>>(attn_op_w1, attn_op_b1, attn_w1, attn_b1, cmb_w1, cmb_b1, ws);
  for (int s = 0; s < T_STEPS; ++s) {
    k_step1<<<512, 256, 0, stream>>>(attn_op_w1, attn_w1, gw_hh, gb_hh, ws, s);
    k_step2<<<2, 256, 0, stream>>>(attn_op_w2, attn_op_b2, attn_w2, attn_b2,
                                   obj_mask, lang_mask, prop, enc, ws, out, s);
    k_step3<<<128, 256, 0, stream>>>(cmb_w1, ws, s);
    k_step4<<<128, 256, 0, stream>>>(cmb_w2, cmb_b2, ws, s);
    k_step5<<<128, 256, 0, stream>>>(gw_ih, gb_ih, ws, s);
  }
  k_final<<<1024, 256, 0, stream>>>(out_w, out_b, ws, out);
}